// Round 1
// baseline (1549.080 us; speedup 1.0000x reference)
//
#include <hip/hip_runtime.h>
#include <math.h>

#define NB 256
#define NN 512
#define SINK_ITERS 50
#define EPSF 1e-10f
#define LOG2E 1.4426950408889634f

__device__ __forceinline__ float hexp2(float x) { return __builtin_amdgcn_exp2f(x); }
__device__ __forceinline__ float hlog2(float x) { return __builtin_amdgcn_logf(x); }

// One block per batch row. Thread t owns row i=t and column j=t.
__global__ __launch_bounds__(NN) void ndcg_main_kernel(const float* __restrict__ y_pred,
                                                       const float* __restrict__ y_true,
                                                       float* __restrict__ ws) {
    const int b = blockIdx.x;
    const int t = threadIdx.x;

    __shared__ float4 packI[NN];   // {scal_i, -m'_i, u_i, 0}
    __shared__ float4 packJ[NN];   // {sL_j, -RL_j, v_j (or v_j*g_j), 0}
    __shared__ float  sS[NN];
    __shared__ float  red[NN];
    __shared__ int    hist[5];

    const float s  = y_pred[b * NN + t];
    const float yt = y_true[b * NN + t];

    sS[t] = s;
    if (t < 5) hist[t] = 0;
    __syncthreads();

    // histogram of y_true values (exact small ints 0..4) for IDCG
    int vi = (int)(yt + 0.5f);
    vi = vi < 0 ? 0 : (vi > 4 ? 4 : vi);
    atomicAdd(&hist[vi], 1);

    // R_j = sum_k |s_j - s_k|
    float R = 0.f;
#pragma unroll 8
    for (int k = 0; k < NN; ++k) R += fabsf(s - sS[k]);

    const float sL    = s * LOG2E;       // log2-domain score
    const float negRL = -R * LOG2E;
    const float scal  = 511.0f - 2.0f * (float)t;

    packJ[t] = make_float4(sL, negRL, 1.0f, 0.f);
    __syncthreads();   // also covers hist atomics

    // row max m'_i (log2 domain) for stable exp2
    float m = -3.4e38f;
#pragma unroll 8
    for (int j = 0; j < NN; ++j) {
        float4 p = packJ[j];
        float a = fmaf(p.x, scal, p.y);
        m = fmaxf(m, a);
    }
    const float negm = -m;

    // softmax denominator Z_i  ->  u_i = 1/Z_i
    float Z = 0.f;
#pragma unroll 8
    for (int j = 0; j < NN; ++j) {
        float4 p = packJ[j];
        float a = fmaf(p.x, scal, p.y) + negm;
        Z += hexp2(a);
    }
    float u = 1.0f / Z;
    float v = 1.0f;

    packI[t] = make_float4(scal, negm, u, 0.f);

    // IDCG: value at sorted position t from histogram cumsums
    const float disc = 1.0f / hlog2((float)t + 2.0f);
    {
        int c4 = hist[4];
        int c3 = c4 + hist[3];
        int c2 = c3 + hist[2];
        int c1 = c2 + hist[1];
        float gain_p = (t < c4) ? 15.f : (t < c3) ? 7.f : (t < c2) ? 3.f :
                       (t < c1) ? 1.f : 0.f;
        red[t] = gain_p * disc;
    }
    __syncthreads();   // packI visible + red ready
    for (int st = NN / 2; st > 0; st >>= 1) {
        if (t < st) red[t] += red[t + st];
        __syncthreads();
    }
    const float idcg = red[0];
    __syncthreads();

    // ---- Sinkhorn in scaling-factor form: M_ij = u_i * v_j * exp2(scal_i*sL_j - RL_j - m'_i)
    for (int it = 0; it < SINK_ITERS; ++it) {
        // column phase: cs_j = v_j * sum_i u_i K_ij
        float acc = 0.f;
#pragma unroll 8
        for (int i = 0; i < NN; ++i) {
            float4 p = packI[i];                       // broadcast read
            float a = fmaf(sL, p.x, negRL) + p.y;
            acc = fmaf(p.z, hexp2(a), acc);
        }
        float cs = v * acc;
        v = v / fmaxf(cs, EPSF);
        packJ[t].z = v;
        __syncthreads();

        // row phase: rs_i = u_i * sum_j v_j K_ij
        acc = 0.f;
#pragma unroll 8
        for (int j = 0; j < NN; ++j) {
            float4 p = packJ[j];                       // broadcast read
            float a = fmaf(p.x, scal, p.y) + negm;
            acc = fmaf(p.z, hexp2(a), acc);
        }
        float rs = u * acc;
        u = u / fmaxf(rs, EPSF);
        packI[t].z = u;
        __syncthreads();
    }

    // ---- epilogue: gt_i = u_i * sum_j (v_j * g_j) K_ij ; ndcg = sum_i gt_i*disc_i / (idcg+eps)
    const float g = hexp2(yt) - 1.0f;                  // 2^yt - 1 (exact)
    packJ[t].z = v * g;
    __syncthreads();

    float acc = 0.f;
#pragma unroll 8
    for (int j = 0; j < NN; ++j) {
        float4 p = packJ[j];
        float a = fmaf(p.x, scal, p.y) + negm;
        acc = fmaf(p.z, hexp2(a), acc);
    }
    red[t] = u * acc * disc;
    __syncthreads();
    for (int st = NN / 2; st > 0; st >>= 1) {
        if (t < st) red[t] += red[t + st];
        __syncthreads();
    }
    if (t == 0) {
        float num = red[0];
        bool ok = (idcg != 0.0f);
        ws[2 * b + 0] = ok ? num / (idcg + EPSF) : 0.f;
        ws[2 * b + 1] = ok ? 1.f : 0.f;
    }
}

__global__ __launch_bounds__(NB) void ndcg_finalize_kernel(const float* __restrict__ ws,
                                                           float* __restrict__ out) {
    const int t = threadIdx.x;
    __shared__ float rn[NB];
    __shared__ float rc[NB];
    rn[t] = ws[2 * t + 0];
    rc[t] = ws[2 * t + 1];
    __syncthreads();
    for (int st = NB / 2; st > 0; st >>= 1) {
        if (t < st) { rn[t] += rn[t + st]; rc[t] += rc[t + st]; }
        __syncthreads();
    }
    if (t == 0) out[0] = -rn[0] / rc[0];
}

extern "C" void kernel_launch(void* const* d_in, const int* in_sizes, int n_in,
                              void* d_out, int out_size, void* d_ws, size_t ws_size,
                              hipStream_t stream) {
    const float* y_pred = (const float*)d_in[0];
    const float* y_true = (const float*)d_in[1];
    float* out = (float*)d_out;
    float* ws  = (float*)d_ws;

    ndcg_main_kernel<<<NB, NN, 0, stream>>>(y_pred, y_true, ws);
    ndcg_finalize_kernel<<<1, NB, 0, stream>>>(ws, out);
}

// Round 2
// 861.965 us; speedup vs baseline: 1.7971x; 1.7971x over previous
//
#include <hip/hip_runtime.h>
#include <math.h>

#define NB 256
#define NN 512
#define NT 1024
#define HNF 128              // float4s (2 entries each) per half: 256 entries
#define SINK_ITERS 50
#define EPSF 1e-10f
#define LOG2E 1.4426950408889634f

__device__ __forceinline__ float hexp2(float x) { return __builtin_amdgcn_exp2f(x); }
__device__ __forceinline__ float hlog2(float x) { return __builtin_amdgcn_logf(x); }

// One block (1024 threads) per batch row. Thread t: element e = t&511, half h = t>>9.
// Matrix entry form: M_ij = exp2( scal_i * sL_j + Vl_j + L_i )
//   pkI pairs {scal_i, L_i}, pkJ pairs {sL_j, Vl_j}; both phases are the same loop.
__global__ __launch_bounds__(NT) void ndcg_main_kernel(const float* __restrict__ y_pred,
                                                       const float* __restrict__ y_true,
                                                       float* __restrict__ ws) {
    const int b = blockIdx.x;
    const int t = threadIdx.x;
    const int e = t & (NN - 1);
    const int h = t >> 9;

    __shared__ float4 pkI[NN / 2];   // {scal_2m, L_2m, scal_2m+1, L_2m+1}
    __shared__ float4 pkJ[NN / 2];   // {sL_2m, Vl_2m, sL_2m+1, Vl_2m+1}
    __shared__ float  red[NT];
    __shared__ float4 sS4[NN / 4];
    __shared__ float  resA;
    __shared__ int    hist[5];

    float2* pkI2 = (float2*)pkI;
    float2* pkJ2 = (float2*)pkJ;
    float*  sS   = (float*)sS4;

    float yt = 0.f;
    if (h == 0) {
        sS[e] = y_pred[b * NN + e];
        yt    = y_true[b * NN + e];
    }
    if (t < 5) hist[t] = 0;
    __syncthreads();

    if (h == 0) {
        int vi = (int)(yt + 0.5f);
        vi = vi < 0 ? 0 : (vi > 4 ? 4 : vi);
        atomicAdd(&hist[vi], 1);
    }

    // ---- R_j = sum_k |s_j - s_k| (split across halves)
    const float se = sS[e];
    float Rp = 0.f;
#pragma unroll 8
    for (int m = h * (NN / 8); m < (h + 1) * (NN / 8); ++m) {
        float4 f = sS4[m];
        Rp += fabsf(se - f.x) + fabsf(se - f.y) + fabsf(se - f.z) + fabsf(se - f.w);
    }
    red[t] = Rp;
    __syncthreads();                         // also covers hist atomics
    if (h == 0) {
        float R = red[t] + red[t + NN];
        pkJ2[e] = make_float2(se * LOG2E, -R * LOG2E);   // Vl = -R*log2e (v=1)
    }
    __syncthreads();

    // ---- IDCG term (histogram cumsum; values are exact ints 0..4)
    float idcg_term = 0.f, disc = 0.f;
    if (h == 0) {
        disc = 1.0f / hlog2((float)e + 2.0f);
        int c4 = hist[4];
        int c3 = c4 + hist[3];
        int c2 = c3 + hist[2];
        int c1 = c2 + hist[1];
        float gp = (e < c4) ? 15.f : (e < c3) ? 7.f : (e < c2) ? 3.f :
                   (e < c1) ? 1.f : 0.f;
        idcg_term = gp * disc;
    }

    // ---- row max m_e (log2 domain)
    const float scal = 511.0f - 2.0f * (float)e;
    float mp = -3.4e38f;
#pragma unroll 8
    for (int m = h * HNF; m < (h + 1) * HNF; ++m) {
        float4 q = pkJ[m];
        mp = fmaxf(mp, fmaf(q.x, scal, q.y));
        mp = fmaxf(mp, fmaf(q.z, scal, q.w));
    }
    red[t] = mp;
    __syncthreads();
    if (h == 0) pkI2[e] = make_float2(scal, -fmaxf(red[t], red[t + NN]));
    __syncthreads();

    // ---- softmax denom -> L_e = -m_e - log2(Z_e)
    const float negm = pkI2[e].y;
    {
        float z0 = 0.f, z1 = 0.f;
#pragma unroll 8
        for (int m = h * HNF; m < (h + 1) * HNF; ++m) {
            float4 q = pkJ[m];
            z0 += hexp2(fmaf(q.x, scal, q.y) + negm);
            z1 += hexp2(fmaf(q.z, scal, q.w) + negm);
        }
        red[t] = z0 + z1;
    }
    __syncthreads();
    if (h == 0) {
        float Z = red[t] + red[t + NN];
        pkI2[e] = make_float2(scal, negm - hlog2(Z));
    }
    __syncthreads();

    // ---- Sinkhorn: both phases are the same symmetric loop
    for (int it = 0; it < SINK_ITERS; ++it) {
        {   // column phase: lane state {sL_e, Vl_e}, broadcast pkI
            float2 me = pkJ2[e];
            float a0 = 0.f, a1 = 0.f;
#pragma unroll 8
            for (int m = h * HNF; m < (h + 1) * HNF; ++m) {
                float4 q = pkI[m];
                a0 += hexp2(fmaf(q.x, me.x, me.y) + q.y);
                a1 += hexp2(fmaf(q.z, me.x, me.y) + q.w);
            }
            red[t] = a0 + a1;
            __syncthreads();
            if (h == 0) {
                float cs = red[t] + red[t + NN];
                pkJ2[e].y = me.y - hlog2(fmaxf(cs, EPSF));
            }
            __syncthreads();
        }
        {   // row phase: lane state {scal_e, L_e}, broadcast pkJ
            float2 me = pkI2[e];
            float a0 = 0.f, a1 = 0.f;
#pragma unroll 8
            for (int m = h * HNF; m < (h + 1) * HNF; ++m) {
                float4 q = pkJ[m];
                a0 += hexp2(fmaf(q.x, me.x, me.y) + q.y);
                a1 += hexp2(fmaf(q.z, me.x, me.y) + q.w);
            }
            red[t] = a0 + a1;
            __syncthreads();
            if (h == 0) {
                float rs = red[t] + red[t + NN];
                pkI2[e].y = me.y - hlog2(fmaxf(rs, EPSF));
            }
            __syncthreads();
        }
    }

    // ---- epilogue: fold gains into Vl (log2(0) = -inf -> exp2 -> 0, safe)
    if (h == 0) {
        float g = hexp2(yt) - 1.0f;          // 2^yt - 1, exact
        pkJ2[e].y += hlog2(g);
    }
    __syncthreads();
    {
        float2 me = pkI2[e];
        float a0 = 0.f, a1 = 0.f;
#pragma unroll 8
        for (int m = h * HNF; m < (h + 1) * HNF; ++m) {
            float4 q = pkJ[m];
            a0 += hexp2(fmaf(q.x, me.x, me.y) + q.y);
            a1 += hexp2(fmaf(q.z, me.x, me.y) + q.w);
        }
        red[t] = a0 + a1;
    }
    __syncthreads();
    float term = 0.f;
    if (h == 0) term = (red[t] + red[t + NN]) * disc;
    __syncthreads();
    red[t] = term;
    __syncthreads();
    for (int st = NT / 2; st > 0; st >>= 1) {
        if (t < st) red[t] += red[t + st];
        __syncthreads();
    }
    if (t == 0) resA = red[0];
    __syncthreads();
    red[t] = idcg_term;                      // 0 for h==1
    __syncthreads();
    for (int st = NT / 2; st > 0; st >>= 1) {
        if (t < st) red[t] += red[t + st];
        __syncthreads();
    }
    if (t == 0) {
        float idcg = red[0];
        bool ok = (idcg != 0.0f);
        ws[2 * b + 0] = ok ? resA / (idcg + EPSF) : 0.f;
        ws[2 * b + 1] = ok ? 1.f : 0.f;
    }
}

__global__ __launch_bounds__(NB) void ndcg_finalize_kernel(const float* __restrict__ ws,
                                                           float* __restrict__ out) {
    const int t = threadIdx.x;
    __shared__ float rn[NB];
    __shared__ float rc[NB];
    rn[t] = ws[2 * t + 0];
    rc[t] = ws[2 * t + 1];
    __syncthreads();
    for (int st = NB / 2; st > 0; st >>= 1) {
        if (t < st) { rn[t] += rn[t + st]; rc[t] += rc[t + st]; }
        __syncthreads();
    }
    if (t == 0) out[0] = -rn[0] / rc[0];
}

extern "C" void kernel_launch(void* const* d_in, const int* in_sizes, int n_in,
                              void* d_out, int out_size, void* d_ws, size_t ws_size,
                              hipStream_t stream) {
    const float* y_pred = (const float*)d_in[0];
    const float* y_true = (const float*)d_in[1];
    float* out = (float*)d_out;
    float* ws  = (float*)d_ws;

    ndcg_main_kernel<<<NB, NT, 0, stream>>>(y_pred, y_true, ws);
    ndcg_finalize_kernel<<<1, NB, 0, stream>>>(ws, out);
}